// Round 8
// baseline (131.463 us; speedup 1.0000x reference)
//
#include <hip/hip_runtime.h>
#include <hip/hip_bf16.h>

typedef __bf16 bf16_t;
typedef __bf16 bf16x8 __attribute__((ext_vector_type(8)));
typedef float f32x4 __attribute__((ext_vector_type(4)));

#define N_NODES 8192
#define N_EDGES 131072
#define HDIM    256

// ---- ws layout ----
// hs0 @ 0 (8,388,608) | hs1 @ 8388608 (8,388,608) | WconvT @ 16777216 (393,216)
// rp @ 17170432 | ds @ 17207296 | dd @ 17272832 | pg @ 17338368

__device__ inline int rowblk_swz(int x) {
  int xcd = x & 7, q = x >> 3;
  return (xcd >> 2) * 128 + (xcd & 3) * 32 + q;
}

__device__ inline float wred(float v) {
#pragma unroll
  for (int m = 32; m; m >>= 1) v += __shfl_xor(v, m);
  return v;
}

// Kernel 1: blocks 0..1023 = first-layer GEMM (self-transposing Wne via LDS);
// blocks 1024..1056 = CSR row pointers; blocks 1057..1824 = WconvT transpose.
__global__ __launch_bounds__(256) void gemm1_prep_k(const float* __restrict__ nf,
                                                    const float* __restrict__ Wne,
                                                    const float* __restrict__ bne,
                                                    const float* __restrict__ Wconv,
                                                    const int* __restrict__ src,
                                                    int* __restrict__ rp,
                                                    bf16_t* __restrict__ WconvT,
                                                    bf16_t* __restrict__ hs0) {
  int x = blockIdx.x, tid = threadIdx.x;
  if (x >= 1024) {
    if (x < 1057) {
      int i = (x - 1024) * 256 + tid;
      if (i < N_NODES) {
        int lo = 0, hi = N_EDGES;
        while (lo < hi) { int mid = (lo + hi) >> 1; if (src[mid] < i) lo = mid + 1; else hi = mid; }
        rp[i] = lo;
      } else if (i == N_NODES) {
        rp[i] = N_EDGES;
      }
    } else {
      int u = (x - 1057) * 256 + tid;   // exactly 768*256 = 196608
      int l = u / 65536, r = u % 65536;
      int n = r / 256, k = r % 256;
      WconvT[l * 65536 + n * 256 + k] = (bf16_t)Wconv[l * 65536 + k * 256 + n];
    }
    return;
  }
  // ---- first-layer GEMM ----
  __shared__ bf16_t Wlds[64 * 128];   // 16 KB, [local col][k], granule-XOR by (lc&15)
  int xb = x & 255, yb = x >> 8;
  int cg0 = yb * 64;
  for (int k = tid >> 6; k < 128; k += 4) {
    int lc = tid & 63;
    float w = Wne[k * 256 + cg0 + lc];
    Wlds[lc * 128 + (((k >> 3) ^ (lc & 15)) << 3) + (k & 7)] = (bf16_t)w;
  }
  int lane = tid & 63, wv = tid >> 6;
  int r0 = (rowblk_swz(xb) * 4 + wv) * 16;
  int l15 = lane & 15, l4 = lane >> 4;
  bf16x8 a[4];
  const float* Ap = nf + (size_t)(r0 + l15) * 128 + 8 * l4;
#pragma unroll
  for (int kk = 0; kk < 4; ++kk) {
    f32x4 a0 = *(const f32x4*)(Ap + 32 * kk);
    f32x4 a1 = *(const f32x4*)(Ap + 32 * kk + 4);
#pragma unroll
    for (int j = 0; j < 4; ++j) { a[kk][j] = (bf16_t)a0[j]; a[kk][4 + j] = (bf16_t)a1[j]; }
  }
  __syncthreads();
#pragma unroll
  for (int ct = 0; ct < 4; ++ct) {
    int lc0 = ct * 16;
    f32x4 acc = {0.f, 0.f, 0.f, 0.f};
#pragma unroll
    for (int kk = 0; kk < 4; ++kk) {
      bf16x8 b = *(const bf16x8*)&Wlds[(lc0 + l15) * 128 + (((4 * kk + l4) ^ l15) << 3)];
      acc = __builtin_amdgcn_mfma_f32_16x16x32_bf16(a[kk], b, acc, 0, 0, 0);
    }
    int col = cg0 + lc0 + l15;
    float bv = bne[col];
#pragma unroll
    for (int i = 0; i < 4; ++i) {
      int row = r0 + 4 * l4 + i;
      size_t idx = (size_t)row * HDIM + col;
      hs0[idx] = (bf16_t)fmaxf(acc[i] + bv, 0.f);
    }
  }
}

// Fused gather + conv GEMM, middle layers; bf16 residual chain. 16 rows/block, grid 1024.
__global__ __launch_bounds__(256) void gconv_k(const bf16_t* __restrict__ hs_in,
                                               const int* __restrict__ rp,
                                               const int* __restrict__ dst,
                                               const bf16_t* __restrict__ BT,
                                               const float* __restrict__ bias,
                                               bf16_t* __restrict__ hs_out) {
  __shared__ bf16_t A_lds[16 * 256];
  int tid = threadIdx.x;
  int x = blockIdx.x;
  int xcd = x & 7, q = x >> 3;
  int b = xcd >> 2;
  int blk = (xcd & 3) * 128 + q;
  int i0 = blk * 16;
  int gang = tid >> 5, l32 = tid & 31;
  const bf16_t* hb = hs_in + (size_t)b * (N_NODES * HDIM) + l32 * 8;
#pragma unroll
  for (int r2 = 0; r2 < 2; ++r2) {
    int lrow = gang * 2 + r2;
    int i = i0 + lrow;
    int e0 = rp[i], e1 = rp[i + 1];
    float acc[8] = {0.f, 0.f, 0.f, 0.f, 0.f, 0.f, 0.f, 0.f};
    int e = e0;
    for (; e + 8 <= e1; e += 8) {
      bf16x8 v[8];
#pragma unroll
      for (int u = 0; u < 8; ++u) v[u] = *(const bf16x8*)(hb + (size_t)dst[e + u] * HDIM);
#pragma unroll
      for (int u = 0; u < 8; ++u)
#pragma unroll
        for (int jj = 0; jj < 8; ++jj) acc[jj] += (float)v[u][jj];
    }
    for (; e < e1; ++e) {
      bf16x8 v = *(const bf16x8*)(hb + (size_t)dst[e] * HDIM);
#pragma unroll
      for (int jj = 0; jj < 8; ++jj) acc[jj] += (float)v[jj];
    }
    bf16x8 o;
#pragma unroll
    for (int jj = 0; jj < 8; ++jj) o[jj] = (bf16_t)acc[jj];
    *(bf16x8*)&A_lds[lrow * 256 + ((l32 ^ (lrow & 7)) * 8)] = o;
  }
  __syncthreads();
  int lane = tid & 63, wv = tid >> 6;
  int l15 = lane & 15, l4 = lane >> 4;
  bf16x8 a[8];
#pragma unroll
  for (int kk = 0; kk < 8; ++kk)
    a[kk] = *(const bf16x8*)&A_lds[l15 * 256 + (((kk * 4 + l4) ^ (l15 & 7)) * 8)];
  int row_base = b * N_NODES + i0;
#pragma unroll
  for (int ct = 0; ct < 4; ++ct) {
    int c0 = wv * 64 + ct * 16;
    const bf16_t* Bp = BT + (size_t)(c0 + l15) * HDIM + 8 * l4;
    f32x4 acc = {0.f, 0.f, 0.f, 0.f};
#pragma unroll
    for (int kk = 0; kk < 8; ++kk)
      acc = __builtin_amdgcn_mfma_f32_16x16x32_bf16(a[kk], *(const bf16x8*)(Bp + 32 * kk), acc, 0, 0, 0);
    int col = c0 + l15;
    float bv = bias[col];
#pragma unroll
    for (int ii = 0; ii < 4; ++ii) {
      int row = row_base + 4 * l4 + ii;
      size_t idx = (size_t)row * HDIM + col;
      float v = fmaxf(acc[ii] + bv, 0.f) + (float)hs_in[idx];
      hs_out[idx] = (bf16_t)v;
    }
  }
}

// Last layer: gconv + fused node heads. Writes out_h f32 + node_health + ds/dd/pg partials.
__global__ __launch_bounds__(256) void gconv_heads_k(const bf16_t* __restrict__ hs_in,
                                                     const int* __restrict__ rp,
                                                     const int* __restrict__ dst,
                                                     const bf16_t* __restrict__ BT,
                                                     const float* __restrict__ bias,
                                                     float* __restrict__ out_h,
                                                     const float* __restrict__ Wcls,
                                                     const float* __restrict__ bcls,
                                                     const float* __restrict__ Wep,
                                                     const float* __restrict__ Wgp,
                                                     float* __restrict__ ds,
                                                     float* __restrict__ dd,
                                                     float* __restrict__ pg,
                                                     float* __restrict__ out_nh) {
  __shared__ bf16_t A_lds[16 * 256];
  __shared__ float red[4][16][8];
  __shared__ float pgrow[16];
  int tid = threadIdx.x;
  int x = blockIdx.x;
  int xcd = x & 7, q = x >> 3;
  int b = xcd >> 2;
  int blk = (xcd & 3) * 128 + q;
  int i0 = blk * 16;
  int gang = tid >> 5, l32 = tid & 31;
  const bf16_t* hb = hs_in + (size_t)b * (N_NODES * HDIM) + l32 * 8;
#pragma unroll
  for (int r2 = 0; r2 < 2; ++r2) {
    int lrow = gang * 2 + r2;
    int i = i0 + lrow;
    int e0 = rp[i], e1 = rp[i + 1];
    float acc[8] = {0.f, 0.f, 0.f, 0.f, 0.f, 0.f, 0.f, 0.f};
    int e = e0;
    for (; e + 8 <= e1; e += 8) {
      bf16x8 v[8];
#pragma unroll
      for (int u = 0; u < 8; ++u) v[u] = *(const bf16x8*)(hb + (size_t)dst[e + u] * HDIM);
#pragma unroll
      for (int u = 0; u < 8; ++u)
#pragma unroll
        for (int jj = 0; jj < 8; ++jj) acc[jj] += (float)v[u][jj];
    }
    for (; e < e1; ++e) {
      bf16x8 v = *(const bf16x8*)(hb + (size_t)dst[e] * HDIM);
#pragma unroll
      for (int jj = 0; jj < 8; ++jj) acc[jj] += (float)v[jj];
    }
    bf16x8 o;
#pragma unroll
    for (int jj = 0; jj < 8; ++jj) o[jj] = (bf16_t)acc[jj];
    *(bf16x8*)&A_lds[lrow * 256 + ((l32 ^ (lrow & 7)) * 8)] = o;
  }
  __syncthreads();
  int lane = tid & 63, wv = tid >> 6;
  int l15 = lane & 15, l4 = lane >> 4;
  bf16x8 a[8];
#pragma unroll
  for (int kk = 0; kk < 8; ++kk)
    a[kk] = *(const bf16x8*)&A_lds[l15 * 256 + (((kk * 4 + l4) ^ (l15 & 7)) * 8)];
  int row_base = b * N_NODES + i0;
  float p[4][8];
#pragma unroll
  for (int ii = 0; ii < 4; ++ii)
#pragma unroll
    for (int hh = 0; hh < 8; ++hh) p[ii][hh] = 0.f;
#pragma unroll
  for (int ct = 0; ct < 4; ++ct) {
    int c0 = wv * 64 + ct * 16;
    const bf16_t* Bp = BT + (size_t)(c0 + l15) * HDIM + 8 * l4;
    f32x4 acc = {0.f, 0.f, 0.f, 0.f};
#pragma unroll
    for (int kk = 0; kk < 8; ++kk)
      acc = __builtin_amdgcn_mfma_f32_16x16x32_bf16(a[kk], *(const bf16x8*)(Bp + 32 * kk), acc, 0, 0, 0);
    int col = c0 + l15;
    float bv = bias[col];
    float wc0 = Wcls[col * 5 + 0], wc1 = Wcls[col * 5 + 1], wc2 = Wcls[col * 5 + 2];
    float wc3 = Wcls[col * 5 + 3], wc4 = Wcls[col * 5 + 4];
    float wes = Wep[col], wed = Wep[256 + col], wgv = Wgp[col];
#pragma unroll
    for (int ii = 0; ii < 4; ++ii) {
      int row = row_base + 4 * l4 + ii;
      size_t idx = (size_t)row * HDIM + col;
      float v = fmaxf(acc[ii] + bv, 0.f) + (float)hs_in[idx];
      out_h[idx] = v;
      p[ii][0] += v * wc0; p[ii][1] += v * wc1; p[ii][2] += v * wc2;
      p[ii][3] += v * wc3; p[ii][4] += v * wc4;
      p[ii][5] += v * wes; p[ii][6] += v * wed; p[ii][7] += v * wgv;
    }
  }
#pragma unroll
  for (int ii = 0; ii < 4; ++ii)
#pragma unroll
    for (int hh = 0; hh < 8; ++hh) {
      float v = p[ii][hh];
#pragma unroll
      for (int m = 8; m; m >>= 1) v += __shfl_xor(v, m);
      p[ii][hh] = v;
    }
  if (l15 == 0) {
#pragma unroll
    for (int ii = 0; ii < 4; ++ii)
#pragma unroll
      for (int hh = 0; hh < 8; ++hh) red[wv][4 * l4 + ii][hh] = p[ii][hh];
  }
  __syncthreads();
  if (tid < 128) {
    int rl = tid >> 3, hh = tid & 7;
    float s = red[0][rl][hh] + red[1][rl][hh] + red[2][rl][hh] + red[3][rl][hh];
    int grow = row_base + rl;
    if (hh < 5)      out_nh[(size_t)grow * 5 + hh] = s + bcls[hh];
    else if (hh == 5) ds[grow] = s;
    else if (hh == 6) dd[grow] = s;
    else              pgrow[rl] = s;
  }
  __syncthreads();
  if (tid == 0) {
    float t = 0.f;
#pragma unroll
    for (int rl = 0; rl < 16; ++rl) t += pgrow[rl];
    pg[b * 512 + blk] = t;
  }
}

// blocks 0..1023: edge sigmoid; 1024..1025: system health.
__global__ __launch_bounds__(256) void edge_sys_k(const float* __restrict__ ds,
                                                  const float* __restrict__ dd,
                                                  const int* __restrict__ src,
                                                  const int* __restrict__ dst,
                                                  const float* __restrict__ bep,
                                                  const float* __restrict__ pg,
                                                  const float* __restrict__ bgp,
                                                  float* __restrict__ out_ep,
                                                  float* __restrict__ out_sys) {
  int x = blockIdx.x;
  if (x < 1024) {
    int t = x * 256 + threadIdx.x;
    int b = t >> 17;
    int e = t & (N_EDGES - 1);
    float v = ds[(b << 13) + src[e]] + dd[(b << 13) + dst[e]] + bep[0];
    out_ep[t] = 1.f / (1.f + expf(-v));
  } else {
    int b = x - 1024, t = threadIdx.x;
    float v = pg[b * 512 + t] + pg[b * 512 + 256 + t];
    v = wred(v);
    __shared__ float sm[4];
    if ((t & 63) == 0) sm[t >> 6] = v;
    __syncthreads();
    if (t == 0) {
      float tot = sm[0] + sm[1] + sm[2] + sm[3];
      float g = tot / (float)N_NODES + bgp[0];
      out_sys[b] = 1.f / (1.f + expf(-g));
    }
  }
}

extern "C" void kernel_launch(void* const* d_in, const int* in_sizes, int n_in,
                              void* d_out, int out_size, void* d_ws, size_t ws_size,
                              hipStream_t stream) {
  (void)in_sizes; (void)n_in; (void)out_size; (void)ws_size;
  const float* nf    = (const float*)d_in[0];
  const int*   src   = (const int*)d_in[3];
  const int*   dst   = (const int*)d_in[4];
  const float* Wne   = (const float*)d_in[5];
  const float* bne   = (const float*)d_in[6];
  const float* Wconv = (const float*)d_in[9];
  const float* bconv = (const float*)d_in[10];
  const float* Wcls  = (const float*)d_in[11];
  const float* bcls  = (const float*)d_in[12];
  const float* Wep   = (const float*)d_in[13];
  const float* bep   = (const float*)d_in[14];
  const float* Wgp   = (const float*)d_in[15];
  const float* bgp   = (const float*)d_in[16];

  char* ws = (char*)d_ws;
  bf16_t* hs0    = (bf16_t*)(ws + 0);
  bf16_t* hs1    = (bf16_t*)(ws + 8388608);
  bf16_t* WconvT = (bf16_t*)(ws + 16777216);
  int*    rp     = (int*)(ws + 17170432);
  float*  ds     = (float*)(ws + 17207296);
  float*  dd     = (float*)(ws + 17272832);
  float*  pg     = (float*)(ws + 17338368);

  float* out     = (float*)d_out;
  float* out_nh  = out;            // 81920
  float* out_ep  = out + 81920;    // 262144
  float* out_sys = out + 344064;   // 2
  float* out_h   = out + 344066;   // 4194304

  hipLaunchKernelGGL(gemm1_prep_k, dim3(1825), dim3(256), 0, stream,
                     nf, Wne, bne, Wconv, src, rp, WconvT, hs0);
  hipLaunchKernelGGL(gconv_k, dim3(1024), dim3(256), 0, stream,
                     hs0, rp, dst, WconvT, bconv, hs1);
  hipLaunchKernelGGL(gconv_k, dim3(1024), dim3(256), 0, stream,
                     hs1, rp, dst, WconvT + 65536, bconv + 256, hs0);
  hipLaunchKernelGGL(gconv_heads_k, dim3(1024), dim3(256), 0, stream,
                     hs0, rp, dst, WconvT + 131072, bconv + 512, out_h,
                     Wcls, bcls, Wep, Wgp, ds, dd, pg, out_nh);
  hipLaunchKernelGGL(edge_sys_k, dim3(1026), dim3(256), 0, stream, ds, dd, src, dst, bep,
                     pg, bgp, out_ep, out_sys);
}

// Round 9
// 114.021 us; speedup vs baseline: 1.1530x; 1.1530x over previous
//
#include <hip/hip_runtime.h>
#include <hip/hip_bf16.h>

typedef __bf16 bf16_t;
typedef __bf16 bf16x8 __attribute__((ext_vector_type(8)));
typedef float f32x4 __attribute__((ext_vector_type(4)));

#define N_NODES 8192
#define N_EDGES 131072
#define HDIM    256

// ---- ws layout ----
// hs0 @ 0 (8,388,608) | hs1 @ 8388608 (8,388,608) | WconvT @ 16777216 (393,216)
// rp @ 17170432 | ds @ 17207296 | dd @ 17272832 | pg @ 17338368 (2x256 f32)

__device__ inline int rowblk_swz(int x) {
  int xcd = x & 7, q = x >> 3;
  return (xcd >> 2) * 128 + (xcd & 3) * 32 + q;
}

__device__ inline float wred(float v) {
#pragma unroll
  for (int m = 32; m; m >>= 1) v += __shfl_xor(v, m);
  return v;
}

// Kernel 1: blocks 0..1023 = first-layer GEMM (self-transposing Wne via LDS);
// blocks 1024..1056 = CSR row pointers; blocks 1057..1104 = WconvT 64x64 tile transpose.
__global__ __launch_bounds__(256) void gemm1_prep_k(const float* __restrict__ nf,
                                                    const float* __restrict__ Wne,
                                                    const float* __restrict__ bne,
                                                    const float* __restrict__ Wconv,
                                                    const int* __restrict__ src,
                                                    int* __restrict__ rp,
                                                    bf16_t* __restrict__ WconvT,
                                                    bf16_t* __restrict__ hs0) {
  __shared__ char smem[64 * 65 * 4];   // union: gemm Wlds (16 KB bf16) / transpose tile (16.6 KB f32)
  int x = blockIdx.x, tid = threadIdx.x;
  if (x >= 1024) {
    if (x < 1057) {
      int i = (x - 1024) * 256 + tid;
      if (i < N_NODES) {
        int lo = 0, hi = N_EDGES;
        while (lo < hi) { int mid = (lo + hi) >> 1; if (src[mid] < i) lo = mid + 1; else hi = mid; }
        rp[i] = lo;
      } else if (i == N_NODES) {
        rp[i] = N_EDGES;
      }
    } else {
      // coalesced transpose: 48 blocks, one 64x64 tile each
      float (*tl)[65] = (float(*)[65])smem;
      int t = x - 1057;                 // 0..47
      int l = t >> 4, tile = t & 15;
      int tr = (tile >> 2) * 64, tc = (tile & 3) * 64;
      int j = tid & 63, i0 = tid >> 6;
#pragma unroll
      for (int s = 0; s < 16; ++s) {
        int i = 4 * s + i0;
        tl[i][j] = Wconv[l * 65536 + (tr + i) * 256 + tc + j];
      }
      __syncthreads();
#pragma unroll
      for (int s = 0; s < 16; ++s) {
        int i = 4 * s + i0;
        WconvT[l * 65536 + (tc + i) * 256 + tr + j] = (bf16_t)tl[j][i];
      }
    }
    return;
  }
  // ---- first-layer GEMM ----
  bf16_t* Wlds = (bf16_t*)smem;        // [64 local cols][128 k], granule-XOR by (lc&15)
  int xb = x & 255, yb = x >> 8;
  int cg0 = yb * 64;
  for (int k = tid >> 6; k < 128; k += 4) {
    int lc = tid & 63;
    float w = Wne[k * 256 + cg0 + lc];
    Wlds[lc * 128 + (((k >> 3) ^ (lc & 15)) << 3) + (k & 7)] = (bf16_t)w;
  }
  int lane = tid & 63, wv = tid >> 6;
  int r0 = (rowblk_swz(xb) * 4 + wv) * 16;
  int l15 = lane & 15, l4 = lane >> 4;
  bf16x8 a[4];
  const float* Ap = nf + (size_t)(r0 + l15) * 128 + 8 * l4;
#pragma unroll
  for (int kk = 0; kk < 4; ++kk) {
    f32x4 a0 = *(const f32x4*)(Ap + 32 * kk);
    f32x4 a1 = *(const f32x4*)(Ap + 32 * kk + 4);
#pragma unroll
    for (int j = 0; j < 4; ++j) { a[kk][j] = (bf16_t)a0[j]; a[kk][4 + j] = (bf16_t)a1[j]; }
  }
  __syncthreads();
#pragma unroll
  for (int ct = 0; ct < 4; ++ct) {
    int lc0 = ct * 16;
    f32x4 acc = {0.f, 0.f, 0.f, 0.f};
#pragma unroll
    for (int kk = 0; kk < 4; ++kk) {
      bf16x8 b = *(const bf16x8*)&Wlds[(lc0 + l15) * 128 + (((4 * kk + l4) ^ l15) << 3)];
      acc = __builtin_amdgcn_mfma_f32_16x16x32_bf16(a[kk], b, acc, 0, 0, 0);
    }
    int col = cg0 + lc0 + l15;
    float bv = bne[col];
#pragma unroll
    for (int i = 0; i < 4; ++i) {
      int row = r0 + 4 * l4 + i;
      size_t idx = (size_t)row * HDIM + col;
      hs0[idx] = (bf16_t)fmaxf(acc[i] + bv, 0.f);
    }
  }
}

// Fused gather + conv GEMM, middle layers. 32 rows/block, 512 threads, grid 512.
__global__ __launch_bounds__(512) void gconv_k(const bf16_t* __restrict__ hs_in,
                                               const int* __restrict__ rp,
                                               const int* __restrict__ dst,
                                               const bf16_t* __restrict__ BT,
                                               const float* __restrict__ bias,
                                               bf16_t* __restrict__ hs_out) {
  __shared__ bf16_t A_lds[32 * 256];   // 16 KB
  int tid = threadIdx.x;
  int x = blockIdx.x;
  int xcd = x & 7, q = x >> 3;         // q: 0..63
  int b = xcd >> 2;
  int blk = (xcd & 3) * 64 + q;        // 0..255 within batch
  int i0 = blk * 32;
  int gang = tid >> 5, l32 = tid & 31; // 16 gangs x 2 rows
  const bf16_t* hb = hs_in + (size_t)b * (N_NODES * HDIM) + l32 * 8;
#pragma unroll
  for (int r2 = 0; r2 < 2; ++r2) {
    int lrow = gang * 2 + r2;
    int i = i0 + lrow;
    int e0 = rp[i], e1 = rp[i + 1];
    float acc[8] = {0.f, 0.f, 0.f, 0.f, 0.f, 0.f, 0.f, 0.f};
    int e = e0;
    for (; e + 8 <= e1; e += 8) {
      bf16x8 v[8];
#pragma unroll
      for (int u = 0; u < 8; ++u) v[u] = *(const bf16x8*)(hb + (size_t)dst[e + u] * HDIM);
#pragma unroll
      for (int u = 0; u < 8; ++u)
#pragma unroll
        for (int jj = 0; jj < 8; ++jj) acc[jj] += (float)v[u][jj];
    }
    for (; e < e1; ++e) {
      bf16x8 v = *(const bf16x8*)(hb + (size_t)dst[e] * HDIM);
#pragma unroll
      for (int jj = 0; jj < 8; ++jj) acc[jj] += (float)v[jj];
    }
    bf16x8 o;
#pragma unroll
    for (int jj = 0; jj < 8; ++jj) o[jj] = (bf16_t)acc[jj];
    *(bf16x8*)&A_lds[lrow * 256 + ((l32 ^ (lrow & 7)) * 8)] = o;
  }
  __syncthreads();
  int lane = tid & 63, wv = tid >> 6;  // 8 waves
  int wr = wv >> 2, wc = wv & 3;       // row-tile, col-group
  int l15 = lane & 15, l4 = lane >> 4;
  bf16x8 a[8];
#pragma unroll
  for (int kk = 0; kk < 8; ++kk)
    a[kk] = *(const bf16x8*)&A_lds[(wr * 16 + l15) * 256 + (((kk * 4 + l4) ^ (l15 & 7)) * 8)];
  int row_base = b * N_NODES + i0 + wr * 16;
#pragma unroll
  for (int ct = 0; ct < 4; ++ct) {
    int c0 = wc * 64 + ct * 16;
    const bf16_t* Bp = BT + (size_t)(c0 + l15) * HDIM + 8 * l4;
    f32x4 acc = {0.f, 0.f, 0.f, 0.f};
#pragma unroll
    for (int kk = 0; kk < 8; ++kk)
      acc = __builtin_amdgcn_mfma_f32_16x16x32_bf16(a[kk], *(const bf16x8*)(Bp + 32 * kk), acc, 0, 0, 0);
    int col = c0 + l15;
    float bv = bias[col];
#pragma unroll
    for (int ii = 0; ii < 4; ++ii) {
      int row = row_base + 4 * l4 + ii;
      size_t idx = (size_t)row * HDIM + col;
      float v = fmaxf(acc[ii] + bv, 0.f) + (float)hs_in[idx];
      hs_out[idx] = (bf16_t)v;
    }
  }
}

// Last layer: gconv + fused node heads. 32 rows/block, 512 threads, grid 512.
__global__ __launch_bounds__(512) void gconv_heads_k(const bf16_t* __restrict__ hs_in,
                                                     const int* __restrict__ rp,
                                                     const int* __restrict__ dst,
                                                     const bf16_t* __restrict__ BT,
                                                     const float* __restrict__ bias,
                                                     float* __restrict__ out_h,
                                                     const float* __restrict__ Wcls,
                                                     const float* __restrict__ bcls,
                                                     const float* __restrict__ Wep,
                                                     const float* __restrict__ Wgp,
                                                     float* __restrict__ ds,
                                                     float* __restrict__ dd,
                                                     float* __restrict__ pg,
                                                     float* __restrict__ out_nh) {
  __shared__ bf16_t A_lds[32 * 256];
  __shared__ float red[2][4][16][8];
  __shared__ float pgrow[32];
  int tid = threadIdx.x;
  int x = blockIdx.x;
  int xcd = x & 7, q = x >> 3;
  int b = xcd >> 2;
  int blk = (xcd & 3) * 64 + q;
  int i0 = blk * 32;
  int gang = tid >> 5, l32 = tid & 31;
  const bf16_t* hb = hs_in + (size_t)b * (N_NODES * HDIM) + l32 * 8;
#pragma unroll
  for (int r2 = 0; r2 < 2; ++r2) {
    int lrow = gang * 2 + r2;
    int i = i0 + lrow;
    int e0 = rp[i], e1 = rp[i + 1];
    float acc[8] = {0.f, 0.f, 0.f, 0.f, 0.f, 0.f, 0.f, 0.f};
    int e = e0;
    for (; e + 8 <= e1; e += 8) {
      bf16x8 v[8];
#pragma unroll
      for (int u = 0; u < 8; ++u) v[u] = *(const bf16x8*)(hb + (size_t)dst[e + u] * HDIM);
#pragma unroll
      for (int u = 0; u < 8; ++u)
#pragma unroll
        for (int jj = 0; jj < 8; ++jj) acc[jj] += (float)v[u][jj];
    }
    for (; e < e1; ++e) {
      bf16x8 v = *(const bf16x8*)(hb + (size_t)dst[e] * HDIM);
#pragma unroll
      for (int jj = 0; jj < 8; ++jj) acc[jj] += (float)v[jj];
    }
    bf16x8 o;
#pragma unroll
    for (int jj = 0; jj < 8; ++jj) o[jj] = (bf16_t)acc[jj];
    *(bf16x8*)&A_lds[lrow * 256 + ((l32 ^ (lrow & 7)) * 8)] = o;
  }
  __syncthreads();
  int lane = tid & 63, wv = tid >> 6;
  int wr = wv >> 2, wc = wv & 3;
  int l15 = lane & 15, l4 = lane >> 4;
  bf16x8 a[8];
#pragma unroll
  for (int kk = 0; kk < 8; ++kk)
    a[kk] = *(const bf16x8*)&A_lds[(wr * 16 + l15) * 256 + (((kk * 4 + l4) ^ (l15 & 7)) * 8)];
  int row_base = b * N_NODES + i0 + wr * 16;
  float p[4][8];
#pragma unroll
  for (int ii = 0; ii < 4; ++ii)
#pragma unroll
    for (int hh = 0; hh < 8; ++hh) p[ii][hh] = 0.f;
#pragma unroll
  for (int ct = 0; ct < 4; ++ct) {
    int c0 = wc * 64 + ct * 16;
    const bf16_t* Bp = BT + (size_t)(c0 + l15) * HDIM + 8 * l4;
    f32x4 acc = {0.f, 0.f, 0.f, 0.f};
#pragma unroll
    for (int kk = 0; kk < 8; ++kk)
      acc = __builtin_amdgcn_mfma_f32_16x16x32_bf16(a[kk], *(const bf16x8*)(Bp + 32 * kk), acc, 0, 0, 0);
    int col = c0 + l15;
    float bv = bias[col];
    float wc0 = Wcls[col * 5 + 0], wc1 = Wcls[col * 5 + 1], wc2 = Wcls[col * 5 + 2];
    float wc3 = Wcls[col * 5 + 3], wc4 = Wcls[col * 5 + 4];
    float wes = Wep[col], wed = Wep[256 + col], wgv = Wgp[col];
#pragma unroll
    for (int ii = 0; ii < 4; ++ii) {
      int row = row_base + 4 * l4 + ii;
      size_t idx = (size_t)row * HDIM + col;
      float v = fmaxf(acc[ii] + bv, 0.f) + (float)hs_in[idx];
      out_h[idx] = v;
      p[ii][0] += v * wc0; p[ii][1] += v * wc1; p[ii][2] += v * wc2;
      p[ii][3] += v * wc3; p[ii][4] += v * wc4;
      p[ii][5] += v * wes; p[ii][6] += v * wed; p[ii][7] += v * wgv;
    }
  }
#pragma unroll
  for (int ii = 0; ii < 4; ++ii)
#pragma unroll
    for (int hh = 0; hh < 8; ++hh) {
      float v = p[ii][hh];
#pragma unroll
      for (int m = 8; m; m >>= 1) v += __shfl_xor(v, m);
      p[ii][hh] = v;
    }
  if (l15 == 0) {
#pragma unroll
    for (int ii = 0; ii < 4; ++ii)
#pragma unroll
      for (int hh = 0; hh < 8; ++hh) red[wr][wc][4 * l4 + ii][hh] = p[ii][hh];
  }
  __syncthreads();
  if (tid < 256) {
    int rl = tid >> 3, hh = tid & 7;   // rl: 0..31
    float s = red[rl >> 4][0][rl & 15][hh] + red[rl >> 4][1][rl & 15][hh] +
              red[rl >> 4][2][rl & 15][hh] + red[rl >> 4][3][rl & 15][hh];
    int grow = b * N_NODES + i0 + rl;
    if (hh < 5)      out_nh[(size_t)grow * 5 + hh] = s + bcls[hh];
    else if (hh == 5) ds[grow] = s;
    else if (hh == 6) dd[grow] = s;
    else              pgrow[rl] = s;
  }
  __syncthreads();
  if (tid == 0) {
    float t = 0.f;
#pragma unroll
    for (int rl = 0; rl < 32; ++rl) t += pgrow[rl];
    pg[b * 256 + blk] = t;
  }
}

// blocks 0..1023: edge sigmoid; 1024..1025: system health (pg: 256 partials per batch).
__global__ __launch_bounds__(256) void edge_sys_k(const float* __restrict__ ds,
                                                  const float* __restrict__ dd,
                                                  const int* __restrict__ src,
                                                  const int* __restrict__ dst,
                                                  const float* __restrict__ bep,
                                                  const float* __restrict__ pg,
                                                  const float* __restrict__ bgp,
                                                  float* __restrict__ out_ep,
                                                  float* __restrict__ out_sys) {
  int x = blockIdx.x;
  if (x < 1024) {
    int t = x * 256 + threadIdx.x;
    int b = t >> 17;
    int e = t & (N_EDGES - 1);
    float v = ds[(b << 13) + src[e]] + dd[(b << 13) + dst[e]] + bep[0];
    out_ep[t] = 1.f / (1.f + expf(-v));
  } else {
    int b = x - 1024, t = threadIdx.x;
    float v = pg[b * 256 + t];
    v = wred(v);
    __shared__ float sm[4];
    if ((t & 63) == 0) sm[t >> 6] = v;
    __syncthreads();
    if (t == 0) {
      float tot = sm[0] + sm[1] + sm[2] + sm[3];
      float g = tot / (float)N_NODES + bgp[0];
      out_sys[b] = 1.f / (1.f + expf(-g));
    }
  }
}

extern "C" void kernel_launch(void* const* d_in, const int* in_sizes, int n_in,
                              void* d_out, int out_size, void* d_ws, size_t ws_size,
                              hipStream_t stream) {
  (void)in_sizes; (void)n_in; (void)out_size; (void)ws_size;
  const float* nf    = (const float*)d_in[0];
  const int*   src   = (const int*)d_in[3];
  const int*   dst   = (const int*)d_in[4];
  const float* Wne   = (const float*)d_in[5];
  const float* bne   = (const float*)d_in[6];
  const float* Wconv = (const float*)d_in[9];
  const float* bconv = (const float*)d_in[10];
  const float* Wcls  = (const float*)d_in[11];
  const float* bcls  = (const float*)d_in[12];
  const float* Wep   = (const float*)d_in[13];
  const float* bep   = (const float*)d_in[14];
  const float* Wgp   = (const float*)d_in[15];
  const float* bgp   = (const float*)d_in[16];

  char* ws = (char*)d_ws;
  bf16_t* hs0    = (bf16_t*)(ws + 0);
  bf16_t* hs1    = (bf16_t*)(ws + 8388608);
  bf16_t* WconvT = (bf16_t*)(ws + 16777216);
  int*    rp     = (int*)(ws + 17170432);
  float*  ds     = (float*)(ws + 17207296);
  float*  dd     = (float*)(ws + 17272832);
  float*  pg     = (float*)(ws + 17338368);

  float* out     = (float*)d_out;
  float* out_nh  = out;            // 81920
  float* out_ep  = out + 81920;    // 262144
  float* out_sys = out + 344064;   // 2
  float* out_h   = out + 344066;   // 4194304

  hipLaunchKernelGGL(gemm1_prep_k, dim3(1105), dim3(256), 0, stream,
                     nf, Wne, bne, Wconv, src, rp, WconvT, hs0);
  hipLaunchKernelGGL(gconv_k, dim3(512), dim3(512), 0, stream,
                     hs0, rp, dst, WconvT, bconv, hs1);
  hipLaunchKernelGGL(gconv_k, dim3(512), dim3(512), 0, stream,
                     hs1, rp, dst, WconvT + 65536, bconv + 256, hs0);
  hipLaunchKernelGGL(gconv_heads_k, dim3(512), dim3(512), 0, stream,
                     hs0, rp, dst, WconvT + 131072, bconv + 512, out_h,
                     Wcls, bcls, Wep, Wgp, ds, dd, pg, out_nh);
  hipLaunchKernelGGL(edge_sys_k, dim3(1026), dim3(256), 0, stream, ds, dd, src, dst, bep,
                     pg, bgp, out_ep, out_sys);
}